// Round 9
// baseline (10892.513 us; speedup 1.0000x reference)
//
#include <hip/hip_runtime.h>
#include <hip/hip_bf16.h>

typedef __bf16 bf16x8 __attribute__((ext_vector_type(8)));
typedef float f32x4 __attribute__((ext_vector_type(4)));
typedef unsigned int u32;
typedef unsigned short u16;

#define NB 64
#define NS 256
#define NE 512
#define NH 512
#define NG 1536
#define NM (NS*NB)

__device__ __forceinline__ float fsig(float x) { return 1.0f/(1.0f + __expf(-x)); }
__device__ __forceinline__ float ftanh(float x) {
  float ax = fabsf(x);
  float t = __expf(-2.0f*ax);
  float r = (1.0f - t)/(1.0f + t);
  return copysignf(r, x);
}

// ---------------- gather: x_sb[(s*64+b)][e] = bf16(emb[src[b][s]][e]) ----------------
__global__ __launch_bounds__(256) void k_gather(const int* __restrict__ src,
                                                const float* __restrict__ emb,
                                                __hip_bfloat16* __restrict__ xsb) {
  int row = blockIdx.x*4 + (threadIdx.x >> 6);
  int lane = threadIdx.x & 63;
  int s = row >> 6, b = row & 63;
  int idx = src[b*NS + s];
  const float* erow = emb + (long)idx*NE + lane*8;
  float4 v0 = *(const float4*)erow;
  float4 v1 = *(const float4*)(erow + 4);
  __hip_bfloat16 tmp[8];
  tmp[0]=__float2bfloat16(v0.x); tmp[1]=__float2bfloat16(v0.y);
  tmp[2]=__float2bfloat16(v0.z); tmp[3]=__float2bfloat16(v0.w);
  tmp[4]=__float2bfloat16(v1.x); tmp[5]=__float2bfloat16(v1.y);
  tmp[6]=__float2bfloat16(v1.z); tmp[7]=__float2bfloat16(v1.w);
  *(uint4*)(xsb + (long)row*NE + lane*8) = *(uint4*)tmp;
}

// ---------------- transpose+cast: WT[g][e] = bf16(W[e][g]), W is 512x1536 ----------------
__global__ __launch_bounds__(256) void k_transpose(const float* i0, const float* i1,
                                                   const float* i2, const float* i3,
                                                   __hip_bfloat16* o0, __hip_bfloat16* o1,
                                                   __hip_bfloat16* o2, __hip_bfloat16* o3) {
  const float* in; __hip_bfloat16* out;
  switch (blockIdx.z) {
    case 0: in=i0; out=o0; break;
    case 1: in=i1; out=o1; break;
    case 2: in=i2; out=o2; break;
    default: in=i3; out=o3; break;
  }
  __shared__ float t[32][33];
  int e0 = blockIdx.x*32, g0 = blockIdx.y*32;
  int r = threadIdx.x >> 5, c = threadIdx.x & 31;
  #pragma unroll
  for (int i=0;i<4;i++) t[r+8*i][c] = in[(long)(e0+r+8*i)*NG + g0+c];
  __syncthreads();
  #pragma unroll
  for (int i=0;i<4;i++) out[(long)(g0+r+8*i)*NE + e0+c] = __float2bfloat16(t[c][r+8*i]);
}

// ---------------- asp_g[b][g] = sum_a asp[b][a]*Wa[a][g] + bias[g]  (f32) ----------------
__global__ __launch_bounds__(256) void k_aspg(const float* __restrict__ asp,
     const float* __restrict__ Wa_f, const float* __restrict__ bias_f,
     const float* __restrict__ Wa_b, const float* __restrict__ bias_b,
     float* __restrict__ aspg_f, float* __restrict__ aspg_b) {
  int dir = blockIdx.z;
  const float* Wa  = dir ? Wa_b  : Wa_f;
  const float* bia = dir ? bias_b : bias_f;
  float* outp = dir ? aspg_b : aspg_f;
  int g = blockIdx.x*256 + threadIdx.x;
  int b0 = blockIdx.y*8;
  __shared__ float la[8*512];
  #pragma unroll
  for (int i=0;i<16;i++){ int idx=i*256+threadIdx.x; la[idx] = asp[(long)(b0 + (idx>>9))*512 + (idx&511)]; }
  __syncthreads();
  float bv = bia[g];
  float acc[8];
  #pragma unroll
  for (int bb=0;bb<8;bb++) acc[bb]=bv;
  for (int a=0;a<512;a++){
    float w = Wa[(long)a*NG + g];
    #pragma unroll
    for (int bb=0;bb<8;bb++) acc[bb] += la[bb*512+a]*w;
  }
  #pragma unroll
  for (int bb=0;bb<8;bb++) outp[(long)(b0+bb)*NG + g] = acc[bb];
}

// ---------------- xg GEMM: A=16384x512 bf16, WT=[1536][512] bf16 ----------------
// Epilogue folds aspg (f32) and writes scan-native layout:
//   xg4[blk=b>>4][s][r=b&15][gate][cin]  (bf16)
__global__ __launch_bounds__(256,3) void k_xgemm(const __hip_bfloat16* __restrict__ A,
                                                 const __hip_bfloat16* __restrict__ WT,
                                                 const float* __restrict__ aspg,
                                                 __hip_bfloat16* __restrict__ C) {
  __shared__ __hip_bfloat16 sA[128*64];
  __shared__ __hip_bfloat16 sB[64*64];
  const int tid = threadIdx.x;
  const int m0 = blockIdx.y*128, n0 = blockIdx.x*64;
  const int wv = tid>>6, lane = tid&63, l16 = lane&15, lq = lane>>4;
  const int wm = wv>>1, wn = wv&1;
  const int srow = tid>>3, sslot = tid&7;   // staging: row within 32-row chunk, 16B slot
  f32x4 acc[4][2] = {};
  for (int kt=0; kt<8; ++kt) {
    int k0 = kt*64;
    __syncthreads();   // previous iter's LDS reads done
    #pragma unroll
    for (int i=0;i<4;i++){
      int row = i*32 + srow;
      const __hip_bfloat16* src = A + (size_t)(m0+row)*512 + k0 + ((sslot ^ (row&7))*8);
      __builtin_amdgcn_global_load_lds(
        (const __attribute__((address_space(1))) void*)src,
        (__attribute__((address_space(3))) void*)((char*)sA + (i*256 + wv*64)*16), 16, 0, 0);
    }
    #pragma unroll
    for (int i=0;i<2;i++){
      int row = i*32 + srow;
      const __hip_bfloat16* src = WT + (size_t)(n0+row)*512 + k0 + ((sslot ^ (row&7))*8);
      __builtin_amdgcn_global_load_lds(
        (const __attribute__((address_space(1))) void*)src,
        (__attribute__((address_space(3))) void*)((char*)sB + (i*256 + wv*64)*16), 16, 0, 0);
    }
    __syncthreads();   // drains vmcnt -> LDS tiles ready
    #pragma unroll
    for (int kk=0; kk<64; kk+=32) {
      bf16x8 af[4]; bf16x8 bfv[2];
      #pragma unroll
      for (int mf=0;mf<4;mf++){
        int row = wm*64 + mf*16 + l16;
        int slot = ((kk>>3) + lq) ^ (row&7);
        af[mf] = *(const bf16x8*)((char*)sA + (row*8 + slot)*16);
      }
      #pragma unroll
      for (int nf=0;nf<2;nf++){
        int row = wn*32 + nf*16 + l16;
        int slot = ((kk>>3) + lq) ^ (row&7);
        bfv[nf] = *(const bf16x8*)((char*)sB + (row*8 + slot)*16);
      }
      #pragma unroll
      for (int mf=0;mf<4;mf++)
        #pragma unroll
        for (int nf=0;nf<2;nf++)
          acc[mf][nf] = __builtin_amdgcn_mfma_f32_16x16x32_bf16(af[mf], bfv[nf], acc[mf][nf], 0,0,0);
    }
  }
  // epilogue: +aspg, write xg4 layout
  #pragma unroll
  for (int mf=0;mf<4;mf++)
    #pragma unroll
    for (int nf=0;nf<2;nf++)
      #pragma unroll
      for (int r=0;r<4;r++){
        int mrow = m0 + wm*64 + mf*16 + lq*4 + r;   // s*64 + b
        int col = n0 + wn*32 + nf*16 + l16;         // 0..1535
        int s = mrow >> 6, b = mrow & 63;
        float v = acc[mf][nf][r] + aspg[(size_t)b*NG + col];
        int gate = col >> 9, cin = col & 511;
        C[((((size_t)(b>>4)*NS + s)*16 + (b&15))*3 + gate)*512 + cin] = __float2bfloat16(v);
      }
}

// ---------------- GRU scan: 8 independent single-WG chains, zero cross-WG sync ----------------
// Chain (dir, blk) = 16 batch rows x 512 h-cols in ONE 1024-thread WG on one CU.
// Full Wh lives in REGISTERS: wave w owns h-cols [32w,32w+32) -> 6 gate-tiles x 16
// k-chunks of bf16x8 = 384 VGPR/lane. h exchange = 32KB LDS ping-pong + s_barrier.
// Per-step: 1536 MFMAs on one CU (~3.1us, MFMA-throughput-bound). No global-memory
// coherence anywhere; only HW-guaranteed intra-WG barriers -> cannot hang.
__global__ __launch_bounds__(1024,1) void k_scan(
   const __hip_bfloat16* __restrict__ xg4_f, const __hip_bfloat16* __restrict__ xg4_b,
   const __hip_bfloat16* __restrict__ whT_f, const __hip_bfloat16* __restrict__ whT_b,
   float* __restrict__ out)
{
  const int id = blockIdx.x;             // 0..7
  const int dir = id >> 2, blk = id & 3;
  const int tid = threadIdx.x;
  const int w = tid >> 6, lane = tid & 63, l16 = lane & 15, lq = lane >> 4;

  const __hip_bfloat16* xg4 = (dir ? xg4_b : xg4_f) + (size_t)blk*NS*16*NG;
  const __hip_bfloat16* whT = dir ? whT_b : whT_f;

  __shared__ __hip_bfloat16 hlds[2][16*512];   // 2 x 16KB, XOR-swizzled rows

  // ---- Wh -> registers: wh[ci*3+g][kc] = whT[g*512 + w*32 + ci*16 + l16][kc*32+lq*8 ..+8]
  bf16x8 wh[6][16];
  #pragma unroll
  for (int ci=0; ci<2; ++ci)
    #pragma unroll
    for (int g=0; g<3; ++g) {
      const __hip_bfloat16* wrow = whT + (size_t)(g*512 + w*32 + ci*16 + l16)*512 + lq*8;
      #pragma unroll
      for (int kc=0; kc<16; ++kc)
        wh[ci*3+g][kc] = *(const bf16x8*)(wrow + kc*32);
    }

  float hreg[2][4] = {{0.f,0.f,0.f,0.f},{0.f,0.f,0.f,0.f}};
  float* out2 = out + (size_t)NB*NS*1024;

  for (int t = 0; t < NS; ++t) {
    int s = dir ? (NS-1-t) : t;
    // (1) xg prefetch to regs (24 scalar bf16 loads; latency hides under MFMA)
    const __hip_bfloat16* xs = xg4 + (size_t)s*16*NG;
    __hip_bfloat16 xr[2][3][4];
    #pragma unroll
    for (int ci=0;ci<2;++ci)
      #pragma unroll
      for (int g=0;g<3;++g)
        #pragma unroll
        for (int r=0;r<4;++r)
          xr[ci][g][r] = xs[((lq*4+r)*3 + g)*512 + w*32 + ci*16 + l16];
    // (2) h(t-1) @ Wh: 96 MFMAs/wave from LDS ping-pong
    f32x4 acc[6] = {};
    if (t > 0) {
      const char* hb = (const char*)hlds[(t&1)^1];
      #pragma unroll
      for (int kc=0; kc<16; ++kc) {
        int byte = (l16*1024 + (kc*32 + lq*8)*2) ^ ((l16&7)<<4);
        bf16x8 af = *(const bf16x8*)(hb + byte);
        #pragma unroll
        for (int u=0; u<6; ++u)
          acc[u] = __builtin_amdgcn_mfma_f32_16x16x32_bf16(af, wh[u][kc], acc[u], 0,0,0);
      }
    }
    // (3) gates + h update; write h(t) to LDS (swizzled) + f32 out store
    char* hw = (char*)hlds[t&1];
    #pragma unroll
    for (int ci=0;ci<2;++ci)
      #pragma unroll
      for (int r=0;r<4;++r) {
        float rg = fsig(__bfloat162float(xr[ci][0][r]) + acc[ci*3+0][r]);
        float zg = fsig(__bfloat162float(xr[ci][1][r]) + acc[ci*3+1][r]);
        float ng = ftanh(__bfloat162float(xr[ci][2][r]) + rg*acc[ci*3+2][r]);
        float h = (1.f - zg)*hreg[ci][r] + zg*ng;
        hreg[ci][r] = h;
        int row = lq*4 + r, col = w*32 + ci*16 + l16;
        int wb = (row*1024 + col*2) ^ ((row&7)<<4);
        *(__hip_bfloat16*)(hw + wb) = __float2bfloat16(h);
        out[((size_t)(blk*16 + row)*NS + s)*1024 + dir*512 + col] = h;
      }
    // (4) LDS-only barrier: no vmcnt drain (out stores flow to HBM lazily)
    asm volatile("s_waitcnt lgkmcnt(0)" ::: "memory");
    __builtin_amdgcn_s_barrier();
    __builtin_amdgcn_sched_barrier(0);
  }
  // encoder_last: concat([hT_b, hT_f]) -> forward writes cols 512.., backward 0..
  #pragma unroll
  for (int ci=0;ci<2;++ci)
    #pragma unroll
    for (int r=0;r<4;++r) {
      int row = lq*4 + r, col = w*32 + ci*16 + l16;
      out2[(size_t)(blk*16 + row)*1024 + (dir ? 0 : 512) + col] = hreg[ci][r];
    }
}

extern "C" void kernel_launch(void* const* d_in, const int* in_sizes, int n_in,
                              void* d_out, int out_size, void* d_ws, size_t ws_size,
                              hipStream_t stream) {
  const int*   src  = (const int*)  d_in[0];
  const float* asp  = (const float*)d_in[2];
  const float* emb  = (const float*)d_in[3];
  const float* Wx_f = (const float*)d_in[4];
  const float* Wh_f = (const float*)d_in[5];
  const float* Wa_f = (const float*)d_in[6];
  const float* b_f  = (const float*)d_in[7];
  const float* Wx_b = (const float*)d_in[8];
  const float* Wh_b = (const float*)d_in[9];
  const float* Wa_b = (const float*)d_in[10];
  const float* b_b  = (const float*)d_in[11];

  char* ws = (char*)d_ws;
  size_t o = 0;
  auto alloc = [&](size_t bytes)->char* { char* p = ws + o; o += (bytes + 255) & ~(size_t)255; return p; };
  __hip_bfloat16* xsb    = (__hip_bfloat16*)alloc((size_t)NM*NE*2);     // 16.8 MB
  __hip_bfloat16* wxT_f  = (__hip_bfloat16*)alloc((size_t)NG*NE*2);
  __hip_bfloat16* wxT_b  = (__hip_bfloat16*)alloc((size_t)NG*NE*2);
  __hip_bfloat16* whT_f  = (__hip_bfloat16*)alloc((size_t)NG*NH*2);
  __hip_bfloat16* whT_b  = (__hip_bfloat16*)alloc((size_t)NG*NH*2);
  float*          aspg_f = (float*)alloc((size_t)NB*NG*4);
  float*          aspg_b = (float*)alloc((size_t)NB*NG*4);
  __hip_bfloat16* xg4_f  = (__hip_bfloat16*)alloc((size_t)NM*NG*2);     // 50.3 MB (xg4 layout)
  __hip_bfloat16* xg4_b  = (__hip_bfloat16*)alloc((size_t)NM*NG*2);     // 50.3 MB

  k_gather<<<dim3(NM/4), 256, 0, stream>>>(src, emb, xsb);
  k_transpose<<<dim3(16,48,4), 256, 0, stream>>>(Wx_f, Wx_b, Wh_f, Wh_b, wxT_f, wxT_b, whT_f, whT_b);
  k_aspg<<<dim3(6,8,2), 256, 0, stream>>>(asp, Wa_f, b_f, Wa_b, b_b, aspg_f, aspg_b);
  k_xgemm<<<dim3(24,128), 256, 0, stream>>>(xsb, wxT_f, aspg_f, xg4_f);
  k_xgemm<<<dim3(24,128), 256, 0, stream>>>(xsb, wxT_b, aspg_b, xg4_b);
  k_scan<<<dim3(8), 1024, 0, stream>>>(xg4_f, xg4_b, whT_f, whT_b, (float*)d_out);
}

// Round 10
// 1661.559 us; speedup vs baseline: 6.5556x; 6.5556x over previous
//
#include <hip/hip_runtime.h>
#include <hip/hip_bf16.h>

typedef __bf16 bf16x8 __attribute__((ext_vector_type(8)));
typedef float f32x4 __attribute__((ext_vector_type(4)));
typedef unsigned int u32;
typedef unsigned short u16;

#define NB 64
#define NS 256
#define NE 512
#define NH 512
#define NG 1536
#define NM (NS*NB)

__device__ __forceinline__ float fsig(float x) { return 1.0f/(1.0f + __expf(-x)); }
__device__ __forceinline__ float ftanh(float x) {
  float ax = fabsf(x);
  float t = __expf(-2.0f*ax);
  float r = (1.0f - t)/(1.0f + t);
  return copysignf(r, x);
}

// write-through (L3-coherent) stores — bypass L1+L2 so no fences are needed (r3-proven)
__device__ __forceinline__ void store_u16_wt(void* p, u32 val, int byteoff) {
  switch (byteoff) {
    case 0:    asm volatile("global_store_short %0, %1, off sc0 sc1" :: "v"(p), "v"(val) : "memory"); break;
    case 1024: asm volatile("global_store_short %0, %1, off offset:1024 sc0 sc1" :: "v"(p), "v"(val) : "memory"); break;
    case 2048: asm volatile("global_store_short %0, %1, off offset:2048 sc0 sc1" :: "v"(p), "v"(val) : "memory"); break;
    default:   asm volatile("global_store_short %0, %1, off offset:3072 sc0 sc1" :: "v"(p), "v"(val) : "memory"); break;
  }
}
__device__ __forceinline__ void store_u32_wt(void* p, u32 val) {
  asm volatile("global_store_dword %0, %1, off sc0 sc1" :: "v"(p), "v"(val) : "memory");
}
#define HLOAD(dst, off) \
  asm volatile("global_load_dwordx4 %0, %1, off offset:" off " sc0 sc1" \
               : "=v"(dst) : "v"(hl) : "memory")

// ---------------- gather: x_sb[(s*64+b)][e] = bf16(emb[src[b][s]][e]) ----------------
__global__ __launch_bounds__(256) void k_gather(const int* __restrict__ src,
                                                const float* __restrict__ emb,
                                                __hip_bfloat16* __restrict__ xsb) {
  int row = blockIdx.x*4 + (threadIdx.x >> 6);
  int lane = threadIdx.x & 63;
  int s = row >> 6, b = row & 63;
  int idx = src[b*NS + s];
  const float* erow = emb + (long)idx*NE + lane*8;
  float4 v0 = *(const float4*)erow;
  float4 v1 = *(const float4*)(erow + 4);
  __hip_bfloat16 tmp[8];
  tmp[0]=__float2bfloat16(v0.x); tmp[1]=__float2bfloat16(v0.y);
  tmp[2]=__float2bfloat16(v0.z); tmp[3]=__float2bfloat16(v0.w);
  tmp[4]=__float2bfloat16(v1.x); tmp[5]=__float2bfloat16(v1.y);
  tmp[6]=__float2bfloat16(v1.z); tmp[7]=__float2bfloat16(v1.w);
  *(uint4*)(xsb + (long)row*NE + lane*8) = *(uint4*)tmp;
}

// ---------------- transpose+cast: WT[g][e] = bf16(W[e][g]), W is 512x1536 ----------------
__global__ __launch_bounds__(256) void k_transpose(const float* i0, const float* i1,
                                                   const float* i2, const float* i3,
                                                   __hip_bfloat16* o0, __hip_bfloat16* o1,
                                                   __hip_bfloat16* o2, __hip_bfloat16* o3) {
  const float* in; __hip_bfloat16* out;
  switch (blockIdx.z) {
    case 0: in=i0; out=o0; break;
    case 1: in=i1; out=o1; break;
    case 2: in=i2; out=o2; break;
    default: in=i3; out=o3; break;
  }
  __shared__ float t[32][33];
  int e0 = blockIdx.x*32, g0 = blockIdx.y*32;
  int r = threadIdx.x >> 5, c = threadIdx.x & 31;
  #pragma unroll
  for (int i=0;i<4;i++) t[r+8*i][c] = in[(long)(e0+r+8*i)*NG + g0+c];
  __syncthreads();
  #pragma unroll
  for (int i=0;i<4;i++) out[(long)(g0+r+8*i)*NE + e0+c] = __float2bfloat16(t[c][r+8*i]);
}

// ---------------- asp_g[b][g] = sum_a asp[b][a]*Wa[a][g] + bias[g]  (f32) ----------------
__global__ __launch_bounds__(256) void k_aspg(const float* __restrict__ asp,
     const float* __restrict__ Wa_f, const float* __restrict__ bias_f,
     const float* __restrict__ Wa_b, const float* __restrict__ bias_b,
     float* __restrict__ aspg_f, float* __restrict__ aspg_b) {
  int dir = blockIdx.z;
  const float* Wa  = dir ? Wa_b  : Wa_f;
  const float* bia = dir ? bias_b : bias_f;
  float* outp = dir ? aspg_b : aspg_f;
  int g = blockIdx.x*256 + threadIdx.x;
  int b0 = blockIdx.y*8;
  __shared__ float la[8*512];
  #pragma unroll
  for (int i=0;i<16;i++){ int idx=i*256+threadIdx.x; la[idx] = asp[(long)(b0 + (idx>>9))*512 + (idx&511)]; }
  __syncthreads();
  float bv = bia[g];
  float acc[8];
  #pragma unroll
  for (int bb=0;bb<8;bb++) acc[bb]=bv;
  for (int a=0;a<512;a++){
    float w = Wa[(long)a*NG + g];
    #pragma unroll
    for (int bb=0;bb<8;bb++) acc[bb] += la[bb*512+a]*w;
  }
  #pragma unroll
  for (int bb=0;bb<8;bb++) outp[(long)(b0+bb)*NG + g] = acc[bb];
}

// ---------------- xg GEMM: A=16384x512 bf16, WT=[1536][512] bf16 -> xg3[jwg][m][gate][16] ----------------
// Epilogue folds aspg (f32 add before bf16 round; r9-proven numerics).
__global__ __launch_bounds__(256,3) void k_xgemm(const __hip_bfloat16* __restrict__ A,
                                                 const __hip_bfloat16* __restrict__ WT,
                                                 const float* __restrict__ aspg,
                                                 __hip_bfloat16* __restrict__ C) {
  __shared__ __hip_bfloat16 sA[128*64];
  __shared__ __hip_bfloat16 sB[64*64];
  const int tid = threadIdx.x;
  const int m0 = blockIdx.y*128, n0 = blockIdx.x*64;
  const int wv = tid>>6, lane = tid&63, l16 = lane&15, lq = lane>>4;
  const int wm = wv>>1, wn = wv&1;
  const int srow = tid>>3, sslot = tid&7;   // staging: row within 32-row chunk, 16B slot
  f32x4 acc[4][2] = {};
  for (int kt=0; kt<8; ++kt) {
    int k0 = kt*64;
    __syncthreads();   // previous iter's LDS reads done
    #pragma unroll
    for (int i=0;i<4;i++){
      int row = i*32 + srow;
      const __hip_bfloat16* src = A + (size_t)(m0+row)*512 + k0 + ((sslot ^ (row&7))*8);
      __builtin_amdgcn_global_load_lds(
        (const __attribute__((address_space(1))) void*)src,
        (__attribute__((address_space(3))) void*)((char*)sA + (i*256 + wv*64)*16), 16, 0, 0);
    }
    #pragma unroll
    for (int i=0;i<2;i++){
      int row = i*32 + srow;
      const __hip_bfloat16* src = WT + (size_t)(n0+row)*512 + k0 + ((sslot ^ (row&7))*8);
      __builtin_amdgcn_global_load_lds(
        (const __attribute__((address_space(1))) void*)src,
        (__attribute__((address_space(3))) void*)((char*)sB + (i*256 + wv*64)*16), 16, 0, 0);
    }
    __syncthreads();   // drains vmcnt -> LDS tiles ready
    #pragma unroll
    for (int kk=0; kk<64; kk+=32) {
      bf16x8 af[4]; bf16x8 bfv[2];
      #pragma unroll
      for (int mf=0;mf<4;mf++){
        int row = wm*64 + mf*16 + l16;
        int slot = ((kk>>3) + lq) ^ (row&7);
        af[mf] = *(const bf16x8*)((char*)sA + (row*8 + slot)*16);
      }
      #pragma unroll
      for (int nf=0;nf<2;nf++){
        int row = wn*32 + nf*16 + l16;
        int slot = ((kk>>3) + lq) ^ (row&7);
        bfv[nf] = *(const bf16x8*)((char*)sB + (row*8 + slot)*16);
      }
      #pragma unroll
      for (int mf=0;mf<4;mf++)
        #pragma unroll
        for (int nf=0;nf<2;nf++)
          acc[mf][nf] = __builtin_amdgcn_mfma_f32_16x16x32_bf16(af[mf], bfv[nf], acc[mf][nf], 0,0,0);
    }
  }
  // epilogue: +aspg, write scan-native layout xg3[jwg][m][gate][c16]
  #pragma unroll
  for (int mf=0;mf<4;mf++)
    #pragma unroll
    for (int nf=0;nf<2;nf++)
      #pragma unroll
      for (int r=0;r<4;r++){
        int mrow = m0 + wm*64 + mf*16 + lq*4 + r;
        int col = n0 + wn*32 + nf*16 + l16;
        float v = acc[mf][nf][r] + aspg[(size_t)(mrow & 63)*NG + col];
        int gate = col >> 9, cin = col & 511;
        int jwg = cin >> 4, c16 = cin & 15;
        C[((size_t)jwg*NM + mrow)*48 + gate*16 + c16] = __float2bfloat16(v);
      }
}

// ---------------- persistent GRU scan, 64 WGs: r3 protocol + eager per-chunk consumption ----------------
// Producer (unchanged from r3): sc0sc1 h-stores -> vmcnt(0) ack -> monotone flag.
// Consumer (new): one ballot-poll reads all 32 flags; every READY producer pair's
// 32-col h chunk is loaded immediately while polling continues for stragglers.
// Loads/issue overlap the producer skew window; only the last slice is serial.
// Accumulation order fixed kc=0..15 -> deterministic. Flags monotone -> self-healing.
__global__ __launch_bounds__(256,1) void k_scan(
   const __hip_bfloat16* __restrict__ xg_f, const __hip_bfloat16* __restrict__ xg_b,
   const __hip_bfloat16* __restrict__ whT_f, const __hip_bfloat16* __restrict__ whT_b,
   __hip_bfloat16* __restrict__ hbase, u32* __restrict__ flags,
   float* __restrict__ out)
{
  const int dir = blockIdx.y;
  const int jwg = blockIdx.x;            // 16 h-cols per wg
  const int tid = threadIdx.x;
  const int wm = tid>>6, lane = tid&63, l16 = lane&15, lq = lane>>4;
  const int mrow = wm*16 + l16;          // batch row this lane consumes (h A-fragment)
  const __hip_bfloat16* xgd = (dir ? xg_b : xg_f) + (size_t)jwg*NM*48;
  const __hip_bfloat16* whT = dir ? whT_b : whT_f;
  __hip_bfloat16* hb = hbase + (size_t)dir*2*NB*NH;
  u32* fl = flags + dir*256;             // [32 jwg][4 wv] u32 flags

  __shared__ __hip_bfloat16 wl[3*16*512];   // 48KB, XOR-swizzled

  #pragma unroll
  for (int i=0;i<12;i++){
    int cc = i*256 + tid;
    int c = cc>>6, slot = cc&63;          // c: 0..47 (gate*16+c16), slot: 16B unit along k
    int gcol = (c>>4)*512 + jwg*16 + (c&15);
    uint4 v = *(const uint4*)(whT + (long)gcol*512 + slot*8);
    *(uint4*)((char*)wl + (c*64 + (slot ^ (c&7)))*16) = v;
  }

  const int jcol = jwg*16 + l16;
  float hreg[4] = {0.f,0.f,0.f,0.f};
  __syncthreads();   // wl ready (only intra-WG barrier in this kernel)

  // lane polls flag of producer jwg'=(lane&31), wave wm (ballot bit j = flag[j])
  u32* fp = fl + (lane & 31)*4 + wm;
  float* out2 = out + (long)NB*NS*1024;

  for (int t=0; t<NS; ++t) {
    int s = dir ? (NS-1-t) : t;
    // (1) xg loads issued BEFORE the wait (overlap the poll)
    const __hip_bfloat16* xs = xgd + (size_t)s*NB*48;
    __hip_bfloat16 xr[3][4];
    #pragma unroll
    for (int g=0;g<3;++g)
      #pragma unroll
      for (int r=0;r<4;++r){
        int b = wm*16 + lq*4 + r;
        xr[g][r] = xs[b*48 + g*16 + l16];
      }
    __builtin_amdgcn_sched_barrier(0);   // pin xg loads before the poll loop
    f32x4 accg[3] = {};
    if (t > 0) {
      const u32 tgt = (u32)t;
      const char* hl = (const char*)(hb + (t&1)*NB*NH) + mrow*1024 + lq*16;
      uint4 hv[16];
      u32 issued = 0;
      // (2) ballot-poll + eager per-chunk load issue
      do {
        u32 f;
        asm volatile("global_load_dword %0, %1, off sc0 sc1\n\ts_waitcnt vmcnt(0)"
                     : "=v"(f) : "v"(fp) : "memory");
        unsigned long long bal = __ballot((int)(f >= tgt));
        u32 pr = (u32)(bal & 0xFFFFFFFFull);          // bit j: producer jwg'=j ready
        u32 pairs = pr & (pr >> 1) & 0x55555555u;     // bit 2kc: chunk kc ready
        u32 cm = 0;
        #pragma unroll
        for (int kc=0;kc<16;++kc) cm |= ((pairs >> (2*kc)) & 1u) << kc;
        u32 newc = cm & ~issued;
        if (newc & 0x0001u) HLOAD(hv[0],  "0");
        if (newc & 0x0002u) HLOAD(hv[1],  "64");
        if (newc & 0x0004u) HLOAD(hv[2],  "128");
        if (newc & 0x0008u) HLOAD(hv[3],  "192");
        if (newc & 0x0010u) HLOAD(hv[4],  "256");
        if (newc & 0x0020u) HLOAD(hv[5],  "320");
        if (newc & 0x0040u) HLOAD(hv[6],  "384");
        if (newc & 0x0080u) HLOAD(hv[7],  "448");
        if (newc & 0x0100u) HLOAD(hv[8],  "512");
        if (newc & 0x0200u) HLOAD(hv[9],  "576");
        if (newc & 0x0400u) HLOAD(hv[10], "640");
        if (newc & 0x0800u) HLOAD(hv[11], "704");
        if (newc & 0x1000u) HLOAD(hv[12], "768");
        if (newc & 0x2000u) HLOAD(hv[13], "832");
        if (newc & 0x4000u) HLOAD(hv[14], "896");
        if (newc & 0x8000u) HLOAD(hv[15], "960");
        issued |= newc;
      } while (issued != 0xFFFFu);
      asm volatile("s_waitcnt vmcnt(0)" ::: "memory");
      __builtin_amdgcn_sched_barrier(0);   // nothing below may hoist above the drain
      // (3) h @ Wh for 3 gates — fixed kc order (deterministic)
      #pragma unroll
      for (int kc=0;kc<16;++kc){
        bf16x8 af;
        __builtin_memcpy(&af, &hv[kc], 16);
        #pragma unroll
        for (int g=0; g<3; ++g){
          int c = g*16 + l16;
          bf16x8 bfr = *(const bf16x8*)((char*)wl + (c*64 + ((kc*4+lq) ^ (c&7)))*16);
          accg[g] = __builtin_amdgcn_mfma_f32_16x16x32_bf16(af, bfr, accg[g], 0,0,0);
        }
      }
    }
    // (4) gates + h update + write-through h store (aspg already folded into xg)
    char* hs = (char*)(hb + ((t+1)&1)*NB*NH) + (size_t)(wm*16 + lq*4)*1024 + jcol*2;
    #pragma unroll
    for (int r=0;r<4;++r){
      float rg = fsig(__bfloat162float(xr[0][r]) + accg[0][r]);
      float zg = fsig(__bfloat162float(xr[1][r]) + accg[1][r]);
      float ng = ftanh(__bfloat162float(xr[2][r]) + rg*accg[2][r]);
      float h = (1.f - zg)*hreg[r] + zg*ng;
      hreg[r] = h;
      __hip_bfloat16 hbf = __float2bfloat16(h);
      u16 bits; __builtin_memcpy(&bits, &hbf, 2);
      store_u16_wt(hs, (u32)bits, r*1024);
    }
    // (5) per-wave publish: h stores acked at L3, then monotone flag
    asm volatile("s_waitcnt vmcnt(0)" ::: "memory");
    if (lane == 0)
      store_u32_wt(fl + jwg*4 + wm, (u32)(t+1));
    // (6) f32 out stores AFTER the flag -> off the critical path
    #pragma unroll
    for (int r=0;r<4;++r){
      int b = wm*16 + lq*4 + r;
      out[((long)b*NS + s)*1024 + dir*512 + jcol] = hreg[r];
    }
  }
  #pragma unroll
  for (int r=0;r<4;++r){
    int b = wm*16 + lq*4 + r;
    out2[(long)b*1024 + (dir ? 0 : 512) + jcol] = hreg[r];  // concat([hT_b, hT_f])
  }
}

extern "C" void kernel_launch(void* const* d_in, const int* in_sizes, int n_in,
                              void* d_out, int out_size, void* d_ws, size_t ws_size,
                              hipStream_t stream) {
  const int*   src  = (const int*)  d_in[0];
  const float* asp  = (const float*)d_in[2];
  const float* emb  = (const float*)d_in[3];
  const float* Wx_f = (const float*)d_in[4];
  const float* Wh_f = (const float*)d_in[5];
  const float* Wa_f = (const float*)d_in[6];
  const float* b_f  = (const float*)d_in[7];
  const float* Wx_b = (const float*)d_in[8];
  const float* Wh_b = (const float*)d_in[9];
  const float* Wa_b = (const float*)d_in[10];
  const float* b_b  = (const float*)d_in[11];

  char* ws = (char*)d_ws;
  size_t o = 0;
  auto alloc = [&](size_t bytes)->char* { char* p = ws + o; o += (bytes + 255) & ~(size_t)255; return p; };
  __hip_bfloat16* xsb    = (__hip_bfloat16*)alloc((size_t)NM*NE*2);     // 16.8 MB
  __hip_bfloat16* wxT_f  = (__hip_bfloat16*)alloc((size_t)NG*NE*2);
  __hip_bfloat16* wxT_b  = (__hip_bfloat16*)alloc((size_t)NG*NE*2);
  __hip_bfloat16* whT_f  = (__hip_bfloat16*)alloc((size_t)NG*NH*2);
  __hip_bfloat16* whT_b  = (__hip_bfloat16*)alloc((size_t)NG*NH*2);
  float*          aspg_f = (float*)alloc((size_t)NB*NG*4);
  float*          aspg_b = (float*)alloc((size_t)NB*NG*4);
  __hip_bfloat16* xg_f   = (__hip_bfloat16*)alloc((size_t)NM*NG*2);     // 50.3 MB (xg3 layout)
  __hip_bfloat16* xg_b   = (__hip_bfloat16*)alloc((size_t)NM*NG*2);     // 50.3 MB
  __hip_bfloat16* hbuf   = (__hip_bfloat16*)alloc((size_t)2*2*NB*NH*2); // 256 KB
  u32*            flags  = (u32*)alloc((size_t)2*256*4);                // 2 KB

  // zero h ping-pong buffers + flags (adjacent allocations) — every launch (graph replay safe)
  hipMemsetAsync(hbuf, 0, (size_t)2*2*NB*NH*2 + (size_t)2*256*4, stream);

  k_gather<<<dim3(NM/4), 256, 0, stream>>>(src, emb, xsb);
  k_transpose<<<dim3(16,48,4), 256, 0, stream>>>(Wx_f, Wx_b, Wh_f, Wh_b, wxT_f, wxT_b, whT_f, whT_b);
  k_aspg<<<dim3(6,8,2), 256, 0, stream>>>(asp, Wa_f, b_f, Wa_b, b_b, aspg_f, aspg_b);
  k_xgemm<<<dim3(24,128), 256, 0, stream>>>(xsb, wxT_f, aspg_f, xg_f);
  k_xgemm<<<dim3(24,128), 256, 0, stream>>>(xsb, wxT_b, aspg_b, xg_b);
  k_scan<<<dim3(32,2), 256, 0, stream>>>(xg_f, xg_b, whT_f, whT_b, hbuf, flags, (float*)d_out);
}